// Round 1
// baseline (185.712 us; speedup 1.0000x reference)
//
#include <hip/hip_runtime.h>

#define B_ROWS 16384
#define D_IN   1024
#define NW1P   2816   // padded GEMM1 N: 10*256 expert + 3*64 gate + 64 pad
#define H2N    128

typedef unsigned short u16;
typedef __attribute__((ext_vector_type(4))) float  f32x4;
typedef __attribute__((ext_vector_type(8))) short  s16x8;
typedef __attribute__((ext_vector_type(8))) unsigned short u16x8;

__device__ __forceinline__ u16 f2bf(float f){
  unsigned int u = __float_as_uint(f);
  u += 0x7FFFu + ((u >> 16) & 1u);
  return (u16)(u >> 16);
}
__device__ __forceinline__ float bf2f(u16 h){
  return __uint_as_float(((unsigned int)h) << 16);
}

// async global->LDS, 16B per lane. LDS dest must be linear (wave base + lane*16).
__device__ __forceinline__ void gload_lds16(const void* gp, void* lp){
  typedef __attribute__((address_space(1))) unsigned int GUI;
  typedef __attribute__((address_space(3))) unsigned int LUI;
  __builtin_amdgcn_global_load_lds((GUI*)(unsigned long long)gp,
                                   (LUI*)(unsigned int)(unsigned long long)lp,
                                   16, 0, 0);
}

// ---------------- weight packing ----------------
// W1T[n][d] (bf16), n in [0,2816): n<2560 -> expert e=n>>8 unit h=n&255 (sW1/dW1 [E][D][H1])
//                                  2560..2751 -> gate g,k (gW1 [3][D][64]); else 0
__global__ void pack_w1_kernel(const float* __restrict__ sW1, const float* __restrict__ dW1,
                               const float* __restrict__ gW1, const float* __restrict__ sb1,
                               const float* __restrict__ db1, const float* __restrict__ gb1,
                               u16* __restrict__ W1T, float* __restrict__ b1c)
{
  __shared__ float t[64*65];
  const int tid = threadIdx.x;
  const int bid = blockIdx.x;          // 44 * 16
  const int ntile = bid >> 4, dtile = bid & 15;
  const int n0 = ntile*64, d0 = dtile*64;
  #pragma unroll
  for (int i=0;i<16;++i){
    int idx = i*256 + tid;
    int dd = idx >> 6, nn = idx & 63;
    int n = n0 + nn, d = d0 + dd;
    float v;
    if (n < 2560){
      int e = n >> 8, h = n & 255;
      v = (e < 4) ? sW1[((size_t)e*D_IN + d)*256 + h]
                  : dW1[((size_t)(e-4)*D_IN + d)*256 + h];
    } else if (n < 2752){
      int t2 = n - 2560; int gg = t2 >> 6, k = t2 & 63;
      v = gW1[((size_t)gg*D_IN + d)*64 + k];
    } else v = 0.f;
    t[nn*65 + dd] = v;
  }
  __syncthreads();
  #pragma unroll
  for (int i=0;i<16;++i){
    int idx = i*256 + tid;
    int nn = idx >> 6, dd = idx & 63;
    W1T[(size_t)(n0+nn)*D_IN + d0 + dd] = f2bf(t[nn*65 + dd]);
  }
  if (dtile == 0 && tid < 64){
    int n = n0 + tid; float v;
    if (n < 2560){ int e = n>>8, h = n&255; v = (e<4)? sb1[e*256+h] : db1[(e-4)*256+h]; }
    else if (n < 2752){ int t2 = n-2560; v = gb1[(t2>>6)*64 + (t2&63)]; }
    else v = 0.f;
    b1c[n] = v;
  }
}

// W2T[e][o][h] (bf16) from sW2/dW2 [E][H1=256][H2=128]; b2c[e][o]
__global__ void pack_w2_kernel(const float* __restrict__ sW2, const float* __restrict__ dW2,
                               const float* __restrict__ sb2, const float* __restrict__ db2,
                               u16* __restrict__ W2T, float* __restrict__ b2c)
{
  __shared__ float t[64*65];
  const int tid = threadIdx.x;
  const int bid = blockIdx.x;          // 10 * 2 * 4
  const int e = bid >> 3, ot = (bid >> 2) & 1, ht = bid & 3;
  const int o0 = ot*64, h0 = ht*64;
  #pragma unroll
  for (int i=0;i<16;++i){
    int idx = i*256 + tid;
    int hh = idx >> 6, oo = idx & 63;
    float v = (e < 4) ? sW2[((size_t)e*256 + h0+hh)*128 + o0+oo]
                      : dW2[((size_t)(e-4)*256 + h0+hh)*128 + o0+oo];
    t[oo*65 + hh] = v;
  }
  __syncthreads();
  #pragma unroll
  for (int i=0;i<16;++i){
    int idx = i*256 + tid;
    int oo = idx >> 6, hh = idx & 63;
    W2T[(size_t)e*32768 + (size_t)(o0+oo)*256 + h0 + hh] = f2bf(t[oo*65 + hh]);
  }
  if (ht == 0 && ot == 0 && tid < 128)
    b2c[e*128 + tid] = (e < 4) ? sb2[e*128 + tid] : db2[(e-4)*128 + tid];
}

__global__ void cast_x_kernel(const float* __restrict__ x, u16* __restrict__ xb)
{
  const size_t i = ((size_t)blockIdx.x*256 + threadIdx.x)*8;
  f32x4 a = *(const f32x4*)(x + i);
  f32x4 b = *(const f32x4*)(x + i + 4);
  u16x8 r;
  r[0]=f2bf(a[0]); r[1]=f2bf(a[1]); r[2]=f2bf(a[2]); r[3]=f2bf(a[3]);
  r[4]=f2bf(b[0]); r[5]=f2bf(b[1]); r[6]=f2bf(b[2]); r[7]=f2bf(b[3]);
  *(u16x8*)(xb + i) = r;
}

// ---------------- GEMM1: Hb[b][n] = relu(Xb @ W1T^T + b1), bf16 out ----------------
// 128x128 tile, BK=32, 4 waves (2x2), 4x4 16x16x32 frags/wave, global_load_lds dbuf.
__global__ __launch_bounds__(256, 2) void gemm1_kernel(
    const u16* __restrict__ Xb, const u16* __restrict__ W1T,
    const float* __restrict__ b1c, u16* __restrict__ Hb)
{
  __shared__ __attribute__((aligned(16))) u16 lds[2][2][128*32];
  const int tid  = threadIdx.x;
  const int lane = tid & 63;
  const int wid  = tid >> 6;
  const int wm   = wid >> 1, wn = wid & 1;
  const int bid  = blockIdx.x;
  const int mt   = bid / 22;
  const int nt   = bid - mt*22;
  const int row0 = mt*128, col0 = nt*128;

  const int sr = tid >> 2;            // staging row within 64-row group
  const int sk = (tid & 3) << 3;      // staging k offset (u16)
  const u16* aSrc = Xb  + (size_t)(row0 + sr)*D_IN + sk;
  const u16* bSrc = W1T + (size_t)(col0 + sr)*D_IN + sk;

  const f32x4 fz = {0.f,0.f,0.f,0.f};
  f32x4 acc[4][4];
  #pragma unroll
  for (int m=0;m<4;++m)
    #pragma unroll
    for (int n=0;n<4;++n) acc[m][n] = fz;

  auto stage = [&](int kt, int buf){
    const u16* ga = aSrc + kt*32;
    const u16* gb = bSrc + kt*32;
    u16* la = &lds[buf][0][tid*8];
    u16* lb = &lds[buf][1][tid*8];
    #pragma unroll
    for (int j=0;j<2;++j){
      gload_lds16(ga + (size_t)j*64*D_IN, la + j*2048);
      gload_lds16(gb + (size_t)j*64*D_IN, lb + j*2048);
    }
  };

  const int fr = lane & 15;           // fragment row/col
  const int ko = (lane >> 4) << 3;    // k chunk 0/8/16/24

  stage(0, 0);
  __syncthreads();

  for (int kt=0; kt<32; ++kt){
    const int buf = kt & 1;
    if (kt+1 < 32) stage(kt+1, buf^1);
    s16x8 af[4], bfv[4];
    #pragma unroll
    for (int m=0;m<4;++m)
      af[m] = *(const s16x8*)&lds[buf][0][(wm*64 + m*16 + fr)*32 + ko];
    #pragma unroll
    for (int n=0;n<4;++n)
      bfv[n] = *(const s16x8*)&lds[buf][1][(wn*64 + n*16 + fr)*32 + ko];
    #pragma unroll
    for (int m=0;m<4;++m)
      #pragma unroll
      for (int n=0;n<4;++n)
        acc[m][n] = __builtin_amdgcn_mfma_f32_16x16x32_bf16(af[m], bfv[n], acc[m][n], 0, 0, 0);
    __syncthreads();
  }

  const int r4 = (lane >> 4) << 2;
  #pragma unroll
  for (int m=0;m<4;++m){
    const int gr = row0 + wm*64 + m*16 + r4;
    #pragma unroll
    for (int n=0;n<4;++n){
      const int gc = col0 + wn*64 + n*16 + fr;
      const float bias = b1c[gc];
      #pragma unroll
      for (int r=0;r<4;++r){
        float v = acc[m][n][r] + bias;
        v = v > 0.f ? v : 0.f;
        Hb[(size_t)(gr + r)*NW1P + gc] = f2bf(v);
      }
    }
  }
}

// ---------------- gates: softmax((relu-hidden) @ gW2 + gb2) ----------------
__global__ void gates_kernel(const u16* __restrict__ Hb, const float* __restrict__ gW2,
                             const float* __restrict__ gb2, float* __restrict__ gts)
{
  __shared__ float wsm[64*6];
  __shared__ float bsm[6];
  const int tid = threadIdx.x;
  const int bid = blockIdx.x;                 // 3 * 64 blocks
  const int g = bid >> 6;
  const int b = ((bid & 63) << 8) + tid;
  if (tid < 6) bsm[tid] = gb2[g*6 + tid];
  for (int i = tid; i < 384; i += 256) wsm[i] = gW2[g*384 + i];
  __syncthreads();
  const u16* gh = Hb + (size_t)b*NW1P + 2560 + g*64;
  float lg[6];
  #pragma unroll
  for (int e=0;e<6;++e) lg[e] = bsm[e];
  #pragma unroll
  for (int k8=0;k8<8;++k8){
    u16x8 hv = *(const u16x8*)&gh[k8*8];
    #pragma unroll
    for (int j=0;j<8;++j){
      const float h = bf2f(hv[j]);
      const int k = k8*8 + j;
      #pragma unroll
      for (int e=0;e<6;++e) lg[e] += h * wsm[k*6 + e];
    }
  }
  float mx = lg[0];
  #pragma unroll
  for (int e=1;e<6;++e) mx = fmaxf(mx, lg[e]);
  float s = 0.f; float p[6];
  #pragma unroll
  for (int e=0;e<6;++e){ p[e] = expf(lg[e]-mx); s += p[e]; }
  const float inv = 1.f / s;
  float* dst = gts + ((size_t)g*B_ROWS + b)*6;
  #pragma unroll
  for (int e=0;e<6;++e) dst[e] = p[e]*inv;
}

// ------- GEMM2 fused with gate-weighted combine: out[g][b][:] = sum_e gate*relu(H_e@W2_e+b2) -------
__global__ __launch_bounds__(256, 2) void gemm2_kernel(
    const u16* __restrict__ Hb, const u16* __restrict__ W2T,
    const float* __restrict__ b2c, const float* __restrict__ gts,
    float* __restrict__ outp)
{
  __shared__ __attribute__((aligned(16))) u16 lds[2][2][128*32];
  const int tid = threadIdx.x;
  const int lane = tid & 63;
  const int wid = tid >> 6;
  const int wm = wid >> 1, wn = wid & 1;
  const int bid = blockIdx.x;                 // 128 * 3
  const int mt = bid / 3;
  const int g  = bid - mt*3;
  const int row0 = mt*128;

  const int sr = tid >> 2;
  const int sk = (tid & 3) << 3;

  const f32x4 fz = {0.f,0.f,0.f,0.f};
  f32x4 oacc[4][4], eacc[4][4];
  #pragma unroll
  for (int m=0;m<4;++m)
    #pragma unroll
    for (int n=0;n<4;++n){ oacc[m][n] = fz; eacc[m][n] = fz; }

  auto stage = [&](int s, int buf){
    const int e  = s >> 3;
    const int ks = s & 7;
    const int eidv = (e < 4) ? e : (g*2 + e);
    const u16* ga = Hb  + (size_t)(row0 + sr)*NW1P + eidv*256 + ks*32 + sk;
    const u16* gb = W2T + (size_t)eidv*32768 + (size_t)sr*256 + ks*32 + sk;
    u16* la = &lds[buf][0][tid*8];
    u16* lb = &lds[buf][1][tid*8];
    #pragma unroll
    for (int j=0;j<2;++j){
      gload_lds16(ga + (size_t)j*64*NW1P, la + j*2048);
      gload_lds16(gb + (size_t)j*64*256,  lb + j*2048);
    }
  };

  const int fr = lane & 15;
  const int ko = (lane >> 4) << 3;
  const int r4 = (lane >> 4) << 2;

  stage(0, 0);
  __syncthreads();

  for (int s=0; s<48; ++s){
    const int buf = s & 1;
    if (s+1 < 48) stage(s+1, buf^1);
    s16x8 af[4], bfv[4];
    #pragma unroll
    for (int m=0;m<4;++m)
      af[m] = *(const s16x8*)&lds[buf][0][(wm*64 + m*16 + fr)*32 + ko];
    #pragma unroll
    for (int n=0;n<4;++n)
      bfv[n] = *(const s16x8*)&lds[buf][1][(wn*64 + n*16 + fr)*32 + ko];
    #pragma unroll
    for (int m=0;m<4;++m)
      #pragma unroll
      for (int n=0;n<4;++n)
        eacc[m][n] = __builtin_amdgcn_mfma_f32_16x16x32_bf16(af[m], bfv[n], eacc[m][n], 0, 0, 0);
    if ((s & 7) == 7){
      const int e = s >> 3;
      const int eidv = (e < 4) ? e : (g*2 + e);
      #pragma unroll
      for (int m=0;m<4;++m){
        const int lr = wm*64 + m*16 + r4;
        float w[4];
        #pragma unroll
        for (int r=0;r<4;++r)
          w[r] = gts[((size_t)g*B_ROWS + row0 + lr + r)*6 + e];
        #pragma unroll
        for (int n=0;n<4;++n){
          const int c = wn*64 + n*16 + fr;
          const float bias = b2c[eidv*128 + c];
          #pragma unroll
          for (int r=0;r<4;++r){
            float v = eacc[m][n][r] + bias;
            v = v > 0.f ? v : 0.f;
            oacc[m][n][r] += w[r]*v;
          }
          eacc[m][n] = fz;
        }
      }
    }
    __syncthreads();
  }

  #pragma unroll
  for (int m=0;m<4;++m){
    const int lr = wm*64 + m*16 + r4;
    #pragma unroll
    for (int n=0;n<4;++n){
      const int c = wn*64 + n*16 + fr;
      #pragma unroll
      for (int r=0;r<4;++r)
        outp[((size_t)g*B_ROWS + row0 + lr + r)*H2N + c] = oacc[m][n][r];
    }
  }
}

extern "C" void kernel_launch(void* const* d_in, const int* in_sizes, int n_in,
                              void* d_out, int out_size, void* d_ws, size_t ws_size,
                              hipStream_t stream)
{
  (void)in_sizes; (void)n_in; (void)out_size; (void)ws_size;
  const float* x   = (const float*)d_in[0];
  const float* sW1 = (const float*)d_in[2];
  const float* sb1 = (const float*)d_in[3];
  const float* sW2 = (const float*)d_in[4];
  const float* sb2 = (const float*)d_in[5];
  const float* dW1 = (const float*)d_in[6];
  const float* db1 = (const float*)d_in[7];
  const float* dW2 = (const float*)d_in[8];
  const float* db2 = (const float*)d_in[9];
  const float* gW1 = (const float*)d_in[10];
  const float* gb1 = (const float*)d_in[11];
  const float* gW2 = (const float*)d_in[12];
  const float* gb2 = (const float*)d_in[13];
  float* outp = (float*)d_out;

  char* ws = (char*)d_ws;
  u16*   Xb  = (u16*  )(ws + 0);          // 16384*1024*2      = 33554432
  u16*   W1T = (u16*  )(ws + 33554432);   // 2816*1024*2       =  5767168
  float* b1c = (float*)(ws + 39321600);   // 2816*4            =    11264
  u16*   W2T = (u16*  )(ws + 39332864);   // 10*128*256*2      =   655360
  float* b2c = (float*)(ws + 39988224);   // 10*128*4          =     5120
  float* gts = (float*)(ws + 39993344);   // 3*16384*6*4       =  1179648
  u16*   Hb  = (u16*  )(ws + 41172992);   // 16384*2816*2      = 92274688  (end ~133.4 MB)

  pack_w1_kernel<<<dim3(704),  dim3(256), 0, stream>>>(sW1,dW1,gW1,sb1,db1,gb1,W1T,b1c);
  pack_w2_kernel<<<dim3(80),   dim3(256), 0, stream>>>(sW2,dW2,sb2,db2,W2T,b2c);
  cast_x_kernel <<<dim3(8192), dim3(256), 0, stream>>>(x, Xb);
  gemm1_kernel  <<<dim3(2816), dim3(256), 0, stream>>>(Xb, W1T, b1c, Hb);
  gates_kernel  <<<dim3(192),  dim3(256), 0, stream>>>(Hb, gW2, gb2, gts);
  gemm2_kernel  <<<dim3(384),  dim3(256), 0, stream>>>(Hb, W2T, b2c, gts, outp);
}

// Round 2
// 170.008 us; speedup vs baseline: 1.0924x; 1.0924x over previous
//
#include <hip/hip_runtime.h>

#define B_ROWS 16384
#define D_IN   1024
#define NW1P   2816   // padded GEMM1 N: 10*256 expert + 3*64 gate + 64 pad
#define H2N    128

typedef unsigned short u16;
typedef __attribute__((ext_vector_type(4))) float  f32x4;
typedef __attribute__((ext_vector_type(8))) short  s16x8;
typedef __attribute__((ext_vector_type(8))) unsigned short u16x8;

__device__ __forceinline__ u16 f2bf(float f){
  unsigned int u = __float_as_uint(f);
  u += 0x7FFFu + ((u >> 16) & 1u);
  return (u16)(u >> 16);
}
__device__ __forceinline__ float bf2f(u16 h){
  return __uint_as_float(((unsigned int)h) << 16);
}

// async global->LDS, 16B per lane. LDS dest must be linear (wave base + lane*16).
__device__ __forceinline__ void gload_lds16(const void* gp, void* lp){
  typedef __attribute__((address_space(1))) unsigned int GUI;
  typedef __attribute__((address_space(3))) unsigned int LUI;
  __builtin_amdgcn_global_load_lds((GUI*)(unsigned long long)gp,
                                   (LUI*)(unsigned int)(unsigned long long)lp,
                                   16, 0, 0);
}

// ---------------- weight packing ----------------
__global__ void pack_w1_kernel(const float* __restrict__ sW1, const float* __restrict__ dW1,
                               const float* __restrict__ gW1, const float* __restrict__ sb1,
                               const float* __restrict__ db1, const float* __restrict__ gb1,
                               u16* __restrict__ W1T, float* __restrict__ b1c)
{
  __shared__ float t[64*65];
  const int tid = threadIdx.x;
  const int bid = blockIdx.x;          // 44 * 16
  const int ntile = bid >> 4, dtile = bid & 15;
  const int n0 = ntile*64, d0 = dtile*64;
  #pragma unroll
  for (int i=0;i<16;++i){
    int idx = i*256 + tid;
    int dd = idx >> 6, nn = idx & 63;
    int n = n0 + nn, d = d0 + dd;
    float v;
    if (n < 2560){
      int e = n >> 8, h = n & 255;
      v = (e < 4) ? sW1[((size_t)e*D_IN + d)*256 + h]
                  : dW1[((size_t)(e-4)*D_IN + d)*256 + h];
    } else if (n < 2752){
      int t2 = n - 2560; int gg = t2 >> 6, k = t2 & 63;
      v = gW1[((size_t)gg*D_IN + d)*64 + k];
    } else v = 0.f;
    t[nn*65 + dd] = v;
  }
  __syncthreads();
  #pragma unroll
  for (int i=0;i<16;++i){
    int idx = i*256 + tid;
    int nn = idx >> 6, dd = idx & 63;
    W1T[(size_t)(n0+nn)*D_IN + d0 + dd] = f2bf(t[nn*65 + dd]);
  }
  if (dtile == 0 && tid < 64){
    int n = n0 + tid; float v;
    if (n < 2560){ int e = n>>8, h = n&255; v = (e<4)? sb1[e*256+h] : db1[(e-4)*256+h]; }
    else if (n < 2752){ int t2 = n-2560; v = gb1[(t2>>6)*64 + (t2&63)]; }
    else v = 0.f;
    b1c[n] = v;
  }
}

__global__ void pack_w2_kernel(const float* __restrict__ sW2, const float* __restrict__ dW2,
                               const float* __restrict__ sb2, const float* __restrict__ db2,
                               u16* __restrict__ W2T, float* __restrict__ b2c)
{
  __shared__ float t[64*65];
  const int tid = threadIdx.x;
  const int bid = blockIdx.x;          // 10 * 2 * 4
  const int e = bid >> 3, ot = (bid >> 2) & 1, ht = bid & 3;
  const int o0 = ot*64, h0 = ht*64;
  #pragma unroll
  for (int i=0;i<16;++i){
    int idx = i*256 + tid;
    int hh = idx >> 6, oo = idx & 63;
    float v = (e < 4) ? sW2[((size_t)e*256 + h0+hh)*128 + o0+oo]
                      : dW2[((size_t)(e-4)*256 + h0+hh)*128 + o0+oo];
    t[oo*65 + hh] = v;
  }
  __syncthreads();
  #pragma unroll
  for (int i=0;i<16;++i){
    int idx = i*256 + tid;
    int oo = idx >> 6, hh = idx & 63;
    W2T[(size_t)e*32768 + (size_t)(o0+oo)*256 + h0 + hh] = f2bf(t[oo*65 + hh]);
  }
  if (ht == 0 && ot == 0 && tid < 128)
    b2c[e*128 + tid] = (e < 4) ? sb2[e*128 + tid] : db2[(e-4)*128 + tid];
}

__global__ void cast_x_kernel(const float* __restrict__ x, u16* __restrict__ xb)
{
  const size_t i = ((size_t)blockIdx.x*256 + threadIdx.x)*8;
  f32x4 a = *(const f32x4*)(x + i);
  f32x4 b = *(const f32x4*)(x + i + 4);
  u16x8 r;
  r[0]=f2bf(a[0]); r[1]=f2bf(a[1]); r[2]=f2bf(a[2]); r[3]=f2bf(a[3]);
  r[4]=f2bf(b[0]); r[5]=f2bf(b[1]); r[6]=f2bf(b[2]); r[7]=f2bf(b[3]);
  *(u16x8*)(xb + i) = r;
}

// ---------------- GEMM1: 256x256 tile, BK=64, 8-phase-style pipelined ----------------
// 8 waves (2m x 4n), wave computes 128x64. A frags reg-cached in ph0 -> A LDS free
// after ph0 barrier -> deep-stage A(t+2) into current buf; B(t+1) into other buf.
// One counted vmcnt(4) per K-tile. XOR slot-swizzle (slot ^= row&7) on both sides.

// stage half H (128 rows): 2 x global_load_lds per thread
#define SGH(srcp, dstB, H) \
  do { \
    gload_lds16((srcp) + (H)*131072,         &L[(dstB) + (H)*8192 + dA]); \
    gload_lds16((srcp) + (H)*131072 + 65536, &L[(dstB) + (H)*8192 + 4096 + dA]); \
  } while(0)

#define PH(AC, BC, N, STG, TAILW) \
  do { \
    bf0 = *(const s16x8*)&L[(BC) + eB0 + (N)*1024]; \
    bf1 = *(const s16x8*)&L[(BC) + eB1 + (N)*1024]; \
    STG; \
    __builtin_amdgcn_s_barrier(); \
    __builtin_amdgcn_s_setprio(1); \
    _Pragma("unroll") \
    for (int m=0;m<8;++m){ \
      acc[m][N] = __builtin_amdgcn_mfma_f32_16x16x32_bf16(a[m][0], bf0, acc[m][N],0,0,0); \
      acc[m][N] = __builtin_amdgcn_mfma_f32_16x16x32_bf16(a[m][1], bf1, acc[m][N],0,0,0); \
    } \
    __builtin_amdgcn_s_setprio(0); \
    TAILW; \
    __builtin_amdgcn_s_barrier(); \
  } while(0)

#define TILE(AC, BC, BN, STGB, STGA, TAILW) \
  do { \
    _Pragma("unroll") \
    for (int m=0;m<8;++m){ \
      a[m][0] = *(const s16x8*)&L[(AC) + eA0 + m*1024]; \
      a[m][1] = *(const s16x8*)&L[(AC) + eA1 + m*1024]; \
    } \
    PH(AC, BC, 0, if (STGB) SGH(bCur, BN, 0), ;); \
    PH(AC, BC, 1, if (STGB) SGH(bCur, BN, 1), ;); \
    PH(AC, BC, 2, if (STGA) SGH(aCur, AC, 0), ;); \
    PH(AC, BC, 3, if (STGA) SGH(aCur, AC, 1), TAILW); \
    bCur += 64; aCur += 64; \
  } while(0)

__global__ __launch_bounds__(512, 2) void gemm1_kernel(
    const u16* __restrict__ Xb, const u16* __restrict__ W1T,
    const float* __restrict__ b1c, u16* __restrict__ Hb)
{
  // regions (u16 elements): A_even=0, B_even=16384, A_odd=32768, B_odd=49152
  __shared__ __attribute__((aligned(16))) u16 L[65536];   // 128 KiB
  const int tid  = threadIdx.x;
  const int lane = tid & 63;
  const int wid  = tid >> 6;
  const int wm   = wid >> 2;          // 0..1
  const int wn   = wid & 3;           // 0..3

  const int bid = blockIdx.x;                         // 704 = 64 mt * 11 nt
  const int swz = (bid & 7)*88 + (bid >> 3);          // XCD swizzle (704 % 8 == 0)
  const int mt  = swz / 11;
  const int nt  = swz - mt*11;
  const int row0 = mt*256, col0 = nt*256;

  const int l15 = lane & 15, l4 = lane >> 4, l7 = lane & 7;
  // ds_read element addrs, slot-swizzled: slot = (kk*4 + l4) ^ (row&7), row&7 == l7
  const int eA0 = ((wm*128 + l15)<<6) + ((( l4   ) ^ l7)<<3);
  const int eA1 = ((wm*128 + l15)<<6) + (((4+l4  ) ^ l7)<<3);
  const int eB0 = ((wn*64  + l15)<<6) + ((( l4   ) ^ l7)<<3);
  const int eB1 = ((wn*64  + l15)<<6) + (((4+l4  ) ^ l7)<<3);

  // staging: thread writes linear dest (row=tid/8, phys slot=tid&7);
  // pre-swizzled source slot = (tid&7) ^ ((tid>>3)&7)
  const int sl   = (tid & 7) ^ ((tid >> 3) & 7);
  const int sOff = ((tid >> 3) << 10) + (sl << 3);
  const int dA   = tid*8;
  const u16* aCur = Xb  + (size_t)row0*D_IN + sOff;
  const u16* bCur = W1T + (size_t)col0*D_IN + sOff;

  f32x4 acc[8][4];
  const f32x4 fz = {0.f,0.f,0.f,0.f};
  #pragma unroll
  for (int m=0;m<8;++m)
    #pragma unroll
    for (int n=0;n<4;++n) acc[m][n] = fz;

  s16x8 a[8][2];
  s16x8 bf0, bf1;

  // prologue: A(0)->A_even, B(0)->B_even, A(1)->A_odd; wait all but A(1)
  SGH(aCur, 0, 0);      SGH(aCur, 0, 1);
  SGH(bCur, 16384, 0);  SGH(bCur, 16384, 1);
  SGH(aCur + 64, 32768, 0); SGH(aCur + 64, 32768, 1);
  aCur += 128;   // -> A(2) source
  bCur += 64;    // -> B(1) source
  asm volatile("s_waitcnt vmcnt(4)" ::: "memory");
  __builtin_amdgcn_s_barrier();

  #pragma unroll 1
  for (int it=0; it<7; ++it){            // tiles 0..13
    TILE(0,     16384, 49152, 1, 1, asm volatile("s_waitcnt vmcnt(4)":::"memory"));
    TILE(32768, 49152, 16384, 1, 1, asm volatile("s_waitcnt vmcnt(4)":::"memory"));
  }
  // tile 14: stage B(15) only, then drain everything needed for tile 15
  TILE(0,     16384, 49152, 1, 0, asm volatile("s_waitcnt vmcnt(0)":::"memory"));
  // tile 15: compute only
  TILE(32768, 49152, 16384, 0, 0, ;);

  // epilogue: bias + relu + bf16 store
  const int r4 = l4 << 2;
  #pragma unroll
  for (int m=0;m<8;++m){
    const int gr = row0 + wm*128 + m*16 + r4;
    #pragma unroll
    for (int n=0;n<4;++n){
      const int gc = col0 + wn*64 + n*16 + l15;
      const float bias = b1c[gc];
      #pragma unroll
      for (int r=0;r<4;++r){
        float v = acc[m][n][r] + bias;
        v = v > 0.f ? v : 0.f;
        Hb[(size_t)(gr + r)*NW1P + gc] = f2bf(v);
      }
    }
  }
}

// ---------------- gates: softmax((relu-hidden) @ gW2 + gb2) ----------------
__global__ void gates_kernel(const u16* __restrict__ Hb, const float* __restrict__ gW2,
                             const float* __restrict__ gb2, float* __restrict__ gts)
{
  __shared__ float wsm[64*6];
  __shared__ float bsm[6];
  const int tid = threadIdx.x;
  const int bid = blockIdx.x;                 // 3 * 64 blocks
  const int g = bid >> 6;
  const int b = ((bid & 63) << 8) + tid;
  if (tid < 6) bsm[tid] = gb2[g*6 + tid];
  for (int i = tid; i < 384; i += 256) wsm[i] = gW2[g*384 + i];
  __syncthreads();
  const u16* gh = Hb + (size_t)b*NW1P + 2560 + g*64;
  float lg[6];
  #pragma unroll
  for (int e=0;e<6;++e) lg[e] = bsm[e];
  #pragma unroll
  for (int k8=0;k8<8;++k8){
    u16x8 hv = *(const u16x8*)&gh[k8*8];
    #pragma unroll
    for (int j=0;j<8;++j){
      const float h = bf2f(hv[j]);
      const int k = k8*8 + j;
      #pragma unroll
      for (int e=0;e<6;++e) lg[e] += h * wsm[k*6 + e];
    }
  }
  float mx = lg[0];
  #pragma unroll
  for (int e=1;e<6;++e) mx = fmaxf(mx, lg[e]);
  float s = 0.f; float p[6];
  #pragma unroll
  for (int e=0;e<6;++e){ p[e] = expf(lg[e]-mx); s += p[e]; }
  const float inv = 1.f / s;
  float* dst = gts + ((size_t)g*B_ROWS + b)*6;
  #pragma unroll
  for (int e=0;e<6;++e) dst[e] = p[e]*inv;
}

// ------- GEMM2 fused with gate-weighted combine -------
__global__ __launch_bounds__(256, 2) void gemm2_kernel(
    const u16* __restrict__ Hb, const u16* __restrict__ W2T,
    const float* __restrict__ b2c, const float* __restrict__ gts,
    float* __restrict__ outp)
{
  __shared__ __attribute__((aligned(16))) u16 lds[2][2][128*32];
  const int tid = threadIdx.x;
  const int lane = tid & 63;
  const int wid = tid >> 6;
  const int wm = wid >> 1, wn = wid & 1;
  const int bid = blockIdx.x;                 // 128 * 3
  const int mt = bid / 3;
  const int g  = bid - mt*3;
  const int row0 = mt*128;

  const int sr = tid >> 2;
  const int sk = (tid & 3) << 3;

  const f32x4 fz = {0.f,0.f,0.f,0.f};
  f32x4 oacc[4][4], eacc[4][4];
  #pragma unroll
  for (int m=0;m<4;++m)
    #pragma unroll
    for (int n=0;n<4;++n){ oacc[m][n] = fz; eacc[m][n] = fz; }

  auto stage = [&](int s, int buf){
    const int e  = s >> 3;
    const int ks = s & 7;
    const int eidv = (e < 4) ? e : (g*2 + e);
    const u16* ga = Hb  + (size_t)(row0 + sr)*NW1P + eidv*256 + ks*32 + sk;
    const u16* gb = W2T + (size_t)eidv*32768 + (size_t)sr*256 + ks*32 + sk;
    u16* la = &lds[buf][0][tid*8];
    u16* lb = &lds[buf][1][tid*8];
    #pragma unroll
    for (int j=0;j<2;++j){
      gload_lds16(ga + (size_t)j*64*NW1P, la + j*2048);
      gload_lds16(gb + (size_t)j*64*256,  lb + j*2048);
    }
  };

  const int fr = lane & 15;
  const int ko = (lane >> 4) << 3;
  const int r4 = (lane >> 4) << 2;

  stage(0, 0);
  __syncthreads();

  for (int s=0; s<48; ++s){
    const int buf = s & 1;
    if (s+1 < 48) stage(s+1, buf^1);
    s16x8 af[4], bfv[4];
    #pragma unroll
    for (int m=0;m<4;++m)
      af[m] = *(const s16x8*)&lds[buf][0][(wm*64 + m*16 + fr)*32 + ko];
    #pragma unroll
    for (int n=0;n<4;++n)
      bfv[n] = *(const s16x8*)&lds[buf][1][(wn*64 + n*16 + fr)*32 + ko];
    #pragma unroll
    for (int m=0;m<4;++m)
      #pragma unroll
      for (int n=0;n<4;++n)
        eacc[m][n] = __builtin_amdgcn_mfma_f32_16x16x32_bf16(af[m], bfv[n], eacc[m][n], 0, 0, 0);
    if ((s & 7) == 7){
      const int e = s >> 3;
      const int eidv = (e < 4) ? e : (g*2 + e);
      #pragma unroll
      for (int m=0;m<4;++m){
        const int lr = wm*64 + m*16 + r4;
        float w[4];
        #pragma unroll
        for (int r=0;r<4;++r)
          w[r] = gts[((size_t)g*B_ROWS + row0 + lr + r)*6 + e];
        #pragma unroll
        for (int n=0;n<4;++n){
          const int c = wn*64 + n*16 + fr;
          const float bias = b2c[eidv*128 + c];
          #pragma unroll
          for (int r=0;r<4;++r){
            float v = eacc[m][n][r] + bias;
            v = v > 0.f ? v : 0.f;
            oacc[m][n][r] += w[r]*v;
          }
          eacc[m][n] = fz;
        }
      }
    }
    __syncthreads();
  }

  #pragma unroll
  for (int m=0;m<4;++m){
    const int lr = wm*64 + m*16 + r4;
    #pragma unroll
    for (int n=0;n<4;++n){
      const int c = wn*64 + n*16 + fr;
      #pragma unroll
      for (int r=0;r<4;++r)
        outp[((size_t)g*B_ROWS + row0 + lr + r)*H2N + c] = oacc[m][n][r];
    }
  }
}

extern "C" void kernel_launch(void* const* d_in, const int* in_sizes, int n_in,
                              void* d_out, int out_size, void* d_ws, size_t ws_size,
                              hipStream_t stream)
{
  (void)in_sizes; (void)n_in; (void)out_size; (void)ws_size;
  const float* x   = (const float*)d_in[0];
  const float* sW1 = (const float*)d_in[2];
  const float* sb1 = (const float*)d_in[3];
  const float* sW2 = (const float*)d_in[4];
  const float* sb2 = (const float*)d_in[5];
  const float* dW1 = (const float*)d_in[6];
  const float* db1 = (const float*)d_in[7];
  const float* dW2 = (const float*)d_in[8];
  const float* db2 = (const float*)d_in[9];
  const float* gW1 = (const float*)d_in[10];
  const float* gb1 = (const float*)d_in[11];
  const float* gW2 = (const float*)d_in[12];
  const float* gb2 = (const float*)d_in[13];
  float* outp = (float*)d_out;

  char* ws = (char*)d_ws;
  u16*   Xb  = (u16*  )(ws + 0);          // 16384*1024*2      = 33554432
  u16*   W1T = (u16*  )(ws + 33554432);   // 2816*1024*2       =  5767168
  float* b1c = (float*)(ws + 39321600);   // 2816*4            =    11264
  u16*   W2T = (u16*  )(ws + 39332864);   // 10*128*256*2      =   655360
  float* b2c = (float*)(ws + 39988224);   // 10*128*4          =     5120
  float* gts = (float*)(ws + 39993344);   // 3*16384*6*4       =  1179648
  u16*   Hb  = (u16*  )(ws + 41172992);   // 16384*2816*2      = 92274688  (end ~133.4 MB)

  pack_w1_kernel<<<dim3(704),  dim3(256), 0, stream>>>(sW1,dW1,gW1,sb1,db1,gb1,W1T,b1c);
  pack_w2_kernel<<<dim3(80),   dim3(256), 0, stream>>>(sW2,dW2,sb2,db2,W2T,b2c);
  cast_x_kernel <<<dim3(8192), dim3(256), 0, stream>>>(x, Xb);
  gemm1_kernel  <<<dim3(704),  dim3(512), 0, stream>>>(Xb, W1T, b1c, Hb);
  gates_kernel  <<<dim3(192),  dim3(256), 0, stream>>>(Hb, gW2, gb2, gts);
  gemm2_kernel  <<<dim3(384),  dim3(256), 0, stream>>>(Hb, W2T, b2c, gts, outp);
}